// Round 1
// baseline (403.022 us; speedup 1.0000x reference)
//
#include <hip/hip_runtime.h>

// Problem constants: B=16, F=128, N=2048
#define B_ 16
#define F_ 128
#define N_ 2048
#define M_TOT (B_ * F_ * N_)   // 4,194,304 elements in emb_in

typedef float f4v __attribute__((ext_vector_type(4)));

// ---------------------------------------------------------------------------
// Kernel 1: fused single pass over emb:
//   d[b,n]    = sum_f v[f] * emb[b,f,n]          (raw dot, unscaled)
//   partials  = per-block (sum, sumsq) over all elements read
// grid = 128 blocks (16 b x 8 n-tiles), block = 256 -> one thread per column.
// Each f-step is a fully coalesced 256B wave load; the std-reduction rides
// along for free on the same data (saves the separate 16.8 MB k_reduce pass).
// ---------------------------------------------------------------------------
__global__ __launch_bounds__(256) void k_stats_dot(const float* __restrict__ emb,
                                                   const float* __restrict__ v,
                                                   float* __restrict__ d,
                                                   float* __restrict__ partials) {
    __shared__ float vs[F_];
    int tid = threadIdx.x;
    if (tid < F_) vs[tid] = v[tid];
    __syncthreads();

    int idx = blockIdx.x * 256 + tid;   // 0 .. B_*N_-1  (column id)
    int b = idx >> 11;                  // / N_
    int n = idx & (N_ - 1);             // % N_
    const float* base = emb + (size_t)b * F_ * N_ + n;

    float acc = 0.f, s = 0.f, q = 0.f;
    #pragma unroll 8
    for (int f = 0; f < F_; ++f) {
        float e = base[(size_t)f * N_];
        acc += vs[f] * e;
        s += e;
        q += e * e;
    }
    d[idx] = acc;

    // wave64 shuffle reduce of (s, q)
    #pragma unroll
    for (int off = 32; off > 0; off >>= 1) {
        s += __shfl_down(s, off);
        q += __shfl_down(q, off);
    }
    __shared__ float ls[4], lq[4];      // 256 threads = 4 waves
    int wave = tid >> 6;
    if ((tid & 63) == 0) { ls[wave] = s; lq[wave] = q; }
    __syncthreads();
    if (tid == 0) {
        partials[2 * blockIdx.x]     = ls[0] + ls[1] + ls[2] + ls[3];
        partials[2 * blockIdx.x + 1] = lq[0] + lq[1] + lq[2] + lq[3];
    }
}

// ---------------------------------------------------------------------------
// Kernel 2: single block reduces 128 partial pairs -> scal[0]=inv_std,
// scal[1]=0.5*bias  (t-scaling is folded into k_out as a free FMA).
// ---------------------------------------------------------------------------
__global__ __launch_bounds__(128) void k_finalize(const float* __restrict__ partials,
                                                  const float* __restrict__ bias,
                                                  float* __restrict__ scal,
                                                  int nblk) {
    int tid = threadIdx.x;
    float s = 0.f, q = 0.f;
    for (int i = tid; i < nblk; i += 128) {
        s += partials[2 * i];
        q += partials[2 * i + 1];
    }
    #pragma unroll
    for (int off = 32; off > 0; off >>= 1) {
        s += __shfl_down(s, off);
        q += __shfl_down(q, off);
    }
    __shared__ float ls[2], lq[2];      // 128 threads = 2 waves
    int wave = tid >> 6;
    if ((tid & 63) == 0) { ls[wave] = s; lq[wave] = q; }
    __syncthreads();
    if (tid == 0) {
        float S = ls[0] + ls[1];
        float Q = lq[0] + lq[1];
        float mean = S / (float)M_TOT;
        // unbiased variance over all elements (torch .std() default, ddof=1)
        float var = (Q - S * mean) / (float)(M_TOT - 1);
        scal[0] = rsqrtf(var);
        scal[1] = 0.5f * bias[0];
    }
}

// ---------------------------------------------------------------------------
// Kernel 3: out[b,i,j] = sigmoid( (d_i*inv+hb) + (d_j*inv+hb) )
// 2048 blocks x 256 threads; each block produces 16 consecutive rows of one
// batch. The j-row fragment (2 float4) is loaded ONCE into registers and
// scaled once, then reused for all 16 rows -> 16x fewer blocks and 16x fewer
// j-row reads than one-block-per-row. Stores are non-temporal (write-once
// 268 MB stream, keep it out of L2).
// ---------------------------------------------------------------------------
__device__ __forceinline__ float fast_sigmoid(float x) {
    float e = __expf(-x);
    return __builtin_amdgcn_rcpf(1.0f + e);
}

#define ROWS_PER_BLOCK 16

__global__ __launch_bounds__(256) void k_out(const float* __restrict__ d,
                                             const float* __restrict__ scal,
                                             float* __restrict__ out) {
    int tid = threadIdx.x;
    int b = blockIdx.x >> 7;                    // 128 i-tiles per batch
    int i0 = (blockIdx.x & 127) << 4;           // * ROWS_PER_BLOCK
    float inv = scal[0];
    float hb  = scal[1];

    const f4v* d4 = (const f4v*)(d + ((size_t)b << 11));
    f4v dj0 = d4[tid];
    f4v dj1 = d4[tid + 256];
    f4v ej0, ej1;
    ej0.x = dj0.x * inv + hb;  ej0.y = dj0.y * inv + hb;
    ej0.z = dj0.z * inv + hb;  ej0.w = dj0.w * inv + hb;
    ej1.x = dj1.x * inv + hb;  ej1.y = dj1.y * inv + hb;
    ej1.z = dj1.z * inv + hb;  ej1.w = dj1.w * inv + hb;

    const float* di_row = d + ((size_t)b << 11) + i0;

    #pragma unroll 4
    for (int r = 0; r < ROWS_PER_BLOCK; ++r) {
        float ei = di_row[r] * inv + hb;        // uniform, L1-broadcast
        size_t row = ((size_t)b << 11) + (size_t)(i0 + r);
        f4v* o4 = (f4v*)(out + row * (size_t)N_);

        f4v r0, r1;
        r0.x = fast_sigmoid(ei + ej0.x);
        r0.y = fast_sigmoid(ei + ej0.y);
        r0.z = fast_sigmoid(ei + ej0.z);
        r0.w = fast_sigmoid(ei + ej0.w);
        r1.x = fast_sigmoid(ei + ej1.x);
        r1.y = fast_sigmoid(ei + ej1.y);
        r1.z = fast_sigmoid(ei + ej1.z);
        r1.w = fast_sigmoid(ei + ej1.w);

        __builtin_nontemporal_store(r0, o4 + tid);
        __builtin_nontemporal_store(r1, o4 + tid + 256);
    }
}

// ---------------------------------------------------------------------------
// Launch
// ---------------------------------------------------------------------------
extern "C" void kernel_launch(void* const* d_in, const int* in_sizes, int n_in,
                              void* d_out, int out_size, void* d_ws, size_t ws_size,
                              hipStream_t stream) {
    // inputs in setup_inputs() order: adj_in (unused), emb_in, v, b
    const float* emb  = (const float*)d_in[1];
    const float* v    = (const float*)d_in[2];
    const float* bias = (const float*)d_in[3];
    float* out = (float*)d_out;

    // workspace layout (floats): [0..255] partials, [256..257] scal, [512..] d
    float* wsf      = (float*)d_ws;
    float* partials = wsf;
    float* scal     = wsf + 256;
    float* dvec     = wsf + 512;    // B_*N_ = 32768 floats

    k_stats_dot<<<(B_ * N_) / 256, 256, 0, stream>>>(emb, v, dvec, partials);
    k_finalize<<<1, 128, 0, stream>>>(partials, bias, scal, (B_ * N_) / 256);
    k_out<<<(B_ * N_) / ROWS_PER_BLOCK, 256, 0, stream>>>(dvec, scal, out);
}